// Round 16
// baseline (191.643 us; speedup 1.0000x reference)
//
#include <hip/hip_runtime.h>
#include <hip/hip_bf16.h>
#include <stdint.h>

typedef __attribute__((ext_vector_type(8))) short bf16x8;
typedef __attribute__((ext_vector_type(4))) float f32x4;

__device__ __forceinline__ unsigned short f2bf(float f) {
  __hip_bfloat16 h = __float2bfloat16(f);
  return *reinterpret_cast<unsigned short*>(&h);
}

__device__ __forceinline__ bf16x8 cvt8(f32x4 lo, f32x4 hi) {
  bf16x8 r;
  r[0] = (short)f2bf(lo[0]); r[1] = (short)f2bf(lo[1]);
  r[2] = (short)f2bf(lo[2]); r[3] = (short)f2bf(lo[3]);
  r[4] = (short)f2bf(hi[0]); r[5] = (short)f2bf(hi[1]);
  r[6] = (short)f2bf(hi[2]); r[7] = (short)f2bf(hi[3]);
  return r;
}

// ---------------- prep: per-block absmax partials for w1/w2 (y=0/1) ----------------
// (x-cast removed: GEMM1 now consumes x as f32 directly.)
__global__ void prep_kernel(const float* __restrict__ w1, const float* __restrict__ w2,
                            int n4w, unsigned int* __restrict__ pmax) {
  const float* w = blockIdx.y ? w2 : w1;
  __shared__ unsigned int red[256];
  unsigned int m = 0u;
  const uint4* w4 = reinterpret_cast<const uint4*>(w);
  for (int i = blockIdx.x * blockDim.x + threadIdx.x; i < n4w;
       i += gridDim.x * blockDim.x) {
    uint4 v = w4[i];
    m = max(m, v.x & 0x7fffffffu);
    m = max(m, v.y & 0x7fffffffu);
    m = max(m, v.z & 0x7fffffffu);
    m = max(m, v.w & 0x7fffffffu);
  }
  red[threadIdx.x] = m;
  __syncthreads();
  for (int s = 128; s > 0; s >>= 1) {
    if ((int)threadIdx.x < s)
      red[threadIdx.x] = max(red[threadIdx.x], red[threadIdx.x + s]);
    __syncthreads();
  }
  if (threadIdx.x == 0) pmax[blockIdx.y * 512 + blockIdx.x] = red[0];
}

// ---------------- fake-quant w1/w2: reduce 512 partials, then quantize ----------------
__global__ void quant2_kernel(const float* __restrict__ w1, const float* __restrict__ w2,
                              int n4, const unsigned int* __restrict__ pmax,
                              const int* __restrict__ bits,
                              unsigned short* __restrict__ o1, unsigned short* __restrict__ o2) {
  __shared__ unsigned int red[256];
  const unsigned int* p = pmax + blockIdx.y * 512;
  red[threadIdx.x] = max(p[threadIdx.x], p[threadIdx.x + 256]);
  __syncthreads();
  for (int s = 128; s > 0; s >>= 1) {
    if ((int)threadIdx.x < s)
      red[threadIdx.x] = max(red[threadIdx.x], red[threadIdx.x + s]);
    __syncthreads();
  }
  const float qmax = (float)((1 << (*bits - 1)) - 1);
  const float scale = __uint_as_float(red[0]) / qmax;

  const float* w = blockIdx.y ? w2 : w1;
  unsigned short* o = blockIdx.y ? o2 : o1;
  const float4* w4 = reinterpret_cast<const float4*>(w);
  ushort4* o4 = reinterpret_cast<ushort4*>(o);
  for (int i = blockIdx.x * blockDim.x + threadIdx.x; i < n4;
       i += gridDim.x * blockDim.x) {
    float4 v = w4[i];
    float a = fminf(fmaxf(rintf(v.x / scale), -qmax), qmax) * scale;
    float b = fminf(fmaxf(rintf(v.y / scale), -qmax), qmax) * scale;
    float c = fminf(fmaxf(rintf(v.z / scale), -qmax), qmax) * scale;
    float d = fminf(fmaxf(rintf(v.w / scale), -qmax), qmax) * scale;
    o4[i] = make_ushort4(f2bf(a), f2bf(b), f2bf(c), f2bf(d));
  }
}

// ---------------- GEMM1: A = x in FP32 (cast fused into LDS-read), B = w1q bf16 ----------------
// Loop structure = r12/r13 proven 2-barrier dbuf, BK=32, counted vmcnt(6).
// A-LDS holds f32 (32KB dbuf): stage = 4 gload_lds chunks of 8 rows x 32 f32,
// source slot pre-swizzled ((lane&7)^(lane>>3)); read = 2x ds_read_b128 per
// fragment at slots (fs*2[+1])^(row&7), then in-register RNE cvt to bf16
// (identical math to the removed cast pass). B staging/read = r12 verbatim.
template<bool RELU, bool BF16_OUT>
__global__ __launch_bounds__(256, 3)
void gemm1_f32a(const float* __restrict__ A,           // [M,K] f32 (= x)
                const unsigned short* __restrict__ B,  // [N,K] bf16 bits
                const float* __restrict__ bias,        // [N]
                void* __restrict__ Cout,               // [M,N] bf16 or f32
                int M, int N, int K, int gx) {
  constexpr int BK = 32, MF = 4;
  __shared__ __attribute__((aligned(16))) float          As[2][128 * BK];
  __shared__ __attribute__((aligned(16))) unsigned short Bs[2][128 * BK];

  // bijective XCD swizzle (T1/m204)
  const int nwg = gridDim.x;
  const int orig = blockIdx.x;
  const int q = nwg >> 3, r = nwg & 7;
  const int xcd = orig & 7, cidx = orig >> 3;
  const int wgid = (xcd < r ? xcd * (q + 1) : r * (q + 1) + (xcd - r) * q) + cidx;
  const int bx = wgid % gx;
  const int by = wgid / gx;

  const int tid = threadIdx.x;
  const int lane = tid & 63;
  const int wave = tid >> 6;
  const int wr = wave >> 1;
  const int wc = wave & 1;
  const long brow = (long)by * 128;
  const long bcol = (long)bx * 128;

  f32x4 acc[MF][4] = {};

  // A staging: chunk = 8 rows x 32 f32 (1KB); lane -> row lane>>3, slot lane&7
  const int sarow = lane >> 3;
  const int saslot = ((lane & 7) ^ (lane >> 3)) * 4;   // f32 offset in row
  // B staging: chunk = 16 rows x 32 bf16 (1KB); lane -> row lane>>2, slot lane&3
  const int sbrow = lane >> 2;
  const int sbslot = ((lane & 3) ^ ((lane >> 3) & 3)) * 8;  // bf16 offset
  const int fr = lane & 15;
  const int fs = lane >> 4;   // logical 16B k-slot

  auto stage = [&](int k0, int b) {
#pragma unroll
    for (int it = 0; it < 4; ++it) {          // A: 16 chunks of 8 rows (f32)
      const int c = it * 4 + wave;
      const float* ga = A + (brow + c * 8 + sarow) * (long)K + k0 + saslot;
      __builtin_amdgcn_global_load_lds(
          (const __attribute__((address_space(1))) void*)ga,
          (__attribute__((address_space(3))) void*)(&As[b][c * 256]), 16, 0, 0);
    }
#pragma unroll
    for (int it = 0; it < 2; ++it) {          // B: 8 chunks of 16 rows (bf16)
      const int c = it * 4 + wave;
      const unsigned short* gb = B + (bcol + c * 16 + sbrow) * (long)K + k0 + sbslot;
      __builtin_amdgcn_global_load_lds(
          (const __attribute__((address_space(1))) void*)gb,
          (__attribute__((address_space(3))) void*)(&Bs[b][c * 512]), 16, 0, 0);
    }
  };

  const int nt = K / BK;
  stage(0, 0);
  stage(BK, 1);

  for (int t = 0; t < nt; ++t) {
    const int b = t & 1;
    // wait for stage(t); stage(t+1)'s 6 loads stay in flight
    if (t < nt - 1) asm volatile("s_waitcnt vmcnt(6)" ::: "memory");
    else            asm volatile("s_waitcnt vmcnt(0)" ::: "memory");
    __builtin_amdgcn_s_barrier();

    const float* asf = &As[b][0];
    const unsigned short* bs = &Bs[b][0];
    bf16x8 a[MF], bb[4];
#pragma unroll
    for (int m = 0; m < MF; ++m) {
      const int row = wr * 64 + m * 16 + fr;
      const float* rb = asf + row * BK;
      const int s0 = (fs * 2) ^ (row & 7);
      const int s1 = (fs * 2 + 1) ^ (row & 7);
      f32x4 lo = *reinterpret_cast<const f32x4*>(rb + s0 * 4);
      f32x4 hi = *reinterpret_cast<const f32x4*>(rb + s1 * 4);
      a[m] = cvt8(lo, hi);
    }
#pragma unroll
    for (int n = 0; n < 4; ++n) {
      const int row = wc * 64 + n * 16 + fr;
      bb[n] = *reinterpret_cast<const bf16x8*>(bs + row * BK + ((fs ^ ((row >> 1) & 3)) * 8));
    }
#pragma unroll
    for (int m = 0; m < MF; ++m)
#pragma unroll
      for (int n = 0; n < 4; ++n)
        acc[m][n] = __builtin_amdgcn_mfma_f32_16x16x32_bf16(a[m], bb[n], acc[m][n], 0, 0, 0);

    asm volatile("s_waitcnt lgkmcnt(0)" ::: "memory");
    __builtin_amdgcn_sched_barrier(0);
    __builtin_amdgcn_s_barrier();
    if (t + 2 < nt) stage((t + 2) * BK, b);
  }

  // epilogue: C/D layout col=lane&15, row=(lane>>4)*4+rr  [m89/m91 verified]
  const int fq = lane >> 4;
#pragma unroll
  for (int n = 0; n < 4; ++n) {
    const long col = bcol + wc * 64 + n * 16 + fr;
    const float bv = bias[col];
#pragma unroll
    for (int m = 0; m < MF; ++m) {
#pragma unroll
      for (int rr = 0; rr < 4; ++rr) {
        const long row = brow + wr * 64 + m * 16 + fq * 4 + rr;
        float v = acc[m][n][rr] + bv;
        if (RELU) v = fmaxf(v, 0.0f);
        if (BF16_OUT)
          ((unsigned short*)Cout)[row * N + col] = f2bf(v);
        else
          ((float*)Cout)[row * N + col] = v;
      }
    }
  }
}

// ---------------- GEMM2: round-11/13 kernel frozen (BM=64, BK=64, 3 blk/CU, setprio) ----------------
template<int BM, bool PRIO, bool RELU, bool BF16_OUT>
__global__ __launch_bounds__(256)
void gemm_bt(const unsigned short* __restrict__ A, const unsigned short* __restrict__ B,
             const float* __restrict__ bias, void* __restrict__ Cout,
             int M, int N, int K, int gx) {
  constexpr int BK = 64;
  constexpr int MF = BM / 32;
  __shared__ __attribute__((aligned(16))) unsigned short As[2][BM * BK];
  __shared__ __attribute__((aligned(16))) unsigned short Bs[2][128 * BK];

  const int nwg = gridDim.x;
  const int orig = blockIdx.x;
  const int q = nwg >> 3, r = nwg & 7;
  const int xcd = orig & 7, cidx = orig >> 3;
  const int wgid = (xcd < r ? xcd * (q + 1) : r * (q + 1) + (xcd - r) * q) + cidx;
  const int bx = wgid % gx;
  const int by = wgid / gx;

  const int tid = threadIdx.x;
  const int lane = tid & 63;
  const int wave = tid >> 6;
  const int wr = wave >> 1;
  const int wc = wave & 1;
  const long brow = (long)by * BM;
  const long bcol = (long)bx * 128;

  f32x4 acc[MF][4] = {};

  const int srow = lane >> 3;
  const int gslot = ((lane & 7) ^ (lane >> 3)) * 8;
  const int fr = lane & 15;
  const int fs = lane >> 4;

  auto stage = [&](int k0, int b) {
#pragma unroll
    for (int it = 0; it < BM / 32; ++it) {
      const int c = it * 4 + wave;
      const unsigned short* ga = A + (brow + c * 8 + srow) * (long)K + k0 + gslot;
      __builtin_amdgcn_global_load_lds(
          (const __attribute__((address_space(1))) void*)ga,
          (__attribute__((address_space(3))) void*)(&As[b][c * 512]), 16, 0, 0);
    }
#pragma unroll
    for (int it = 0; it < 4; ++it) {
      const int c = it * 4 + wave;
      const unsigned short* gb = B + (bcol + c * 8 + srow) * (long)K + k0 + gslot;
      __builtin_amdgcn_global_load_lds(
          (const __attribute__((address_space(1))) void*)gb,
          (__attribute__((address_space(3))) void*)(&Bs[b][c * 512]), 16, 0, 0);
    }
  };

  const int nt = K / BK;
  stage(0, 0);
  stage(BK, 1);

  for (int t = 0; t < nt; ++t) {
    const int b = t & 1;
    if (t < nt - 1) {
      if constexpr (BM == 128) asm volatile("s_waitcnt vmcnt(8)" ::: "memory");
      else                     asm volatile("s_waitcnt vmcnt(6)" ::: "memory");
    } else {
      asm volatile("s_waitcnt vmcnt(0)" ::: "memory");
    }
    __builtin_amdgcn_s_barrier();

    const unsigned short* as = &As[b][0];
    const unsigned short* bs = &Bs[b][0];
#pragma unroll
    for (int kk = 0; kk < 2; ++kk) {
      const int s = kk * 4 + fs;
      bf16x8 a[MF], bb[4];
#pragma unroll
      for (int m = 0; m < MF; ++m) {
        const int row = wr * (MF * 16) + m * 16 + fr;
        a[m] = *reinterpret_cast<const bf16x8*>(as + row * BK + ((s ^ (row & 7)) * 8));
      }
#pragma unroll
      for (int n = 0; n < 4; ++n) {
        const int row = wc * 64 + n * 16 + fr;
        bb[n] = *reinterpret_cast<const bf16x8*>(bs + row * BK + ((s ^ (row & 7)) * 8));
      }
      if (PRIO) __builtin_amdgcn_s_setprio(1);
#pragma unroll
      for (int m = 0; m < MF; ++m)
#pragma unroll
        for (int n = 0; n < 4; ++n)
          acc[m][n] = __builtin_amdgcn_mfma_f32_16x16x32_bf16(a[m], bb[n], acc[m][n], 0, 0, 0);
      if (PRIO) __builtin_amdgcn_s_setprio(0);
    }

    asm volatile("s_waitcnt lgkmcnt(0)" ::: "memory");
    __builtin_amdgcn_sched_barrier(0);
    __builtin_amdgcn_s_barrier();
    if (t + 2 < nt) stage((t + 2) * BK, b);
  }

  const int fq = lane >> 4;
#pragma unroll
  for (int n = 0; n < 4; ++n) {
    const long col = bcol + wc * 64 + n * 16 + fr;
    const float bv = bias[col];
#pragma unroll
    for (int m = 0; m < MF; ++m) {
#pragma unroll
      for (int rr = 0; rr < 4; ++rr) {
        const long row = brow + wr * (MF * 16) + m * 16 + fq * 4 + rr;
        float v = acc[m][n][rr] + bv;
        if (RELU) v = fmaxf(v, 0.0f);
        if (BF16_OUT)
          ((unsigned short*)Cout)[row * N + col] = f2bf(v);
        else
          ((float*)Cout)[row * N + col] = v;
      }
    }
  }
}

extern "C" void kernel_launch(void* const* d_in, const int* in_sizes, int n_in,
                              void* d_out, int out_size, void* d_ws, size_t ws_size,
                              hipStream_t stream) {
  const float* x  = (const float*)d_in[0];
  const float* w1 = (const float*)d_in[1];
  const float* b1 = (const float*)d_in[2];
  const float* w2 = (const float*)d_in[3];
  const float* b2 = (const float*)d_in[4];
  const int* bits = (const int*)d_in[5];

  const int M = 64 * 196;  // 12544 tokens
  const int D = 768, H = 3072;
  const int nw1 = H * D;

  char* ws = (char*)d_ws;
  unsigned short* w1q = (unsigned short*)(ws + 256);
  unsigned short* w2q = (unsigned short*)(ws + 256 + (size_t)nw1 * 2);
  unsigned short* hb  = (unsigned short*)(ws + 256 + (size_t)nw1 * 4);
  // pmax[2][512] aliased over hb's head: dead by the time GEMM1 writes hb
  // (prep -> quant2 -> GEMM1 are stream-serial; rewritten every call).
  unsigned int* pmax = (unsigned int*)hb;

  prep_kernel<<<dim3(512, 2), 256, 0, stream>>>(w1, w2, nw1 / 4, pmax);
  quant2_kernel<<<dim3(512, 2), 256, 0, stream>>>(w1, w2, nw1 / 4, pmax, bits, w1q, w2q);

  // GEMM1: h = relu(x @ w1q^T + b1), x consumed as f32 (cast fused);
  // [12544,3072] bf16 out ; 24x98 = 2352 blocks, nt=24, 48KB LDS -> 3 blk/CU
  gemm1_f32a<true, true><<<(H / 128) * (M / 128), 256, 0, stream>>>(
      x, w1q, b1, hb, M, H, D, H / 128);
  // GEMM2: out = h @ w2q^T + b2, [12544,768] f32 ; 6x196 = 1176 blocks, nt=48
  gemm_bt<64, true, false, false><<<(D / 128) * (M / 64), 256, 0, stream>>>(
      hb, w2q, b2, d_out, M, D, H, D / 128);
}

// Round 17
// 184.340 us; speedup vs baseline: 1.0396x; 1.0396x over previous
//
#include <hip/hip_runtime.h>
#include <hip/hip_bf16.h>
#include <stdint.h>

typedef __attribute__((ext_vector_type(8))) short bf16x8;
typedef __attribute__((ext_vector_type(4))) float f32x4;

__device__ __forceinline__ unsigned short f2bf(float f) {
  __hip_bfloat16 h = __float2bfloat16(f);
  return *reinterpret_cast<unsigned short*>(&h);
}

// ---------------- prep: per-block absmax partials (y=0/1) + x->bf16 cast (y=2) ----------------
__global__ void prep_kernel(const float* __restrict__ w1, const float* __restrict__ w2,
                            const float* __restrict__ x, int n4w, int n4x,
                            unsigned int* __restrict__ pmax,
                            unsigned short* __restrict__ ox) {
  if (blockIdx.y == 2) {
    const float4* x4 = reinterpret_cast<const float4*>(x);
    ushort4* o4 = reinterpret_cast<ushort4*>(ox);
    for (int i = blockIdx.x * blockDim.x + threadIdx.x; i < n4x;
         i += gridDim.x * blockDim.x) {
      float4 v = x4[i];
      o4[i] = make_ushort4(f2bf(v.x), f2bf(v.y), f2bf(v.z), f2bf(v.w));
    }
    return;
  }
  const float* w = blockIdx.y ? w2 : w1;
  __shared__ unsigned int red[256];
  unsigned int m = 0u;
  const uint4* w4 = reinterpret_cast<const uint4*>(w);
  for (int i = blockIdx.x * blockDim.x + threadIdx.x; i < n4w;
       i += gridDim.x * blockDim.x) {
    uint4 v = w4[i];
    m = max(m, v.x & 0x7fffffffu);
    m = max(m, v.y & 0x7fffffffu);
    m = max(m, v.z & 0x7fffffffu);
    m = max(m, v.w & 0x7fffffffu);
  }
  red[threadIdx.x] = m;
  __syncthreads();
  for (int s = 128; s > 0; s >>= 1) {
    if ((int)threadIdx.x < s)
      red[threadIdx.x] = max(red[threadIdx.x], red[threadIdx.x + s]);
    __syncthreads();
  }
  if (threadIdx.x == 0) pmax[blockIdx.y * 512 + blockIdx.x] = red[0];
}

// ---------------- fake-quant w1/w2: reduce 512 partials, then quantize ----------------
__global__ void quant2_kernel(const float* __restrict__ w1, const float* __restrict__ w2,
                              int n4, const unsigned int* __restrict__ pmax,
                              const int* __restrict__ bits,
                              unsigned short* __restrict__ o1, unsigned short* __restrict__ o2) {
  __shared__ unsigned int red[256];
  const unsigned int* p = pmax + blockIdx.y * 512;
  red[threadIdx.x] = max(p[threadIdx.x], p[threadIdx.x + 256]);
  __syncthreads();
  for (int s = 128; s > 0; s >>= 1) {
    if ((int)threadIdx.x < s)
      red[threadIdx.x] = max(red[threadIdx.x], red[threadIdx.x + s]);
    __syncthreads();
  }
  const float qmax = (float)((1 << (*bits - 1)) - 1);
  const float scale = __uint_as_float(red[0]) / qmax;

  const float* w = blockIdx.y ? w2 : w1;
  unsigned short* o = blockIdx.y ? o2 : o1;
  const float4* w4 = reinterpret_cast<const float4*>(w);
  ushort4* o4 = reinterpret_cast<ushort4*>(o);
  for (int i = blockIdx.x * blockDim.x + threadIdx.x; i < n4;
       i += gridDim.x * blockDim.x) {
    float4 v = w4[i];
    float a = fminf(fmaxf(rintf(v.x / scale), -qmax), qmax) * scale;
    float b = fminf(fmaxf(rintf(v.y / scale), -qmax), qmax) * scale;
    float c = fminf(fmaxf(rintf(v.z / scale), -qmax), qmax) * scale;
    float d = fminf(fmaxf(rintf(v.w / scale), -qmax), qmax) * scale;
    o4[i] = make_ushort4(f2bf(a), f2bf(b), f2bf(c), f2bf(d));
  }
}

// ---------------- GEMM1: 128x128, BK=32, dbuf + counted vmcnt(4) (r12/r13 proven) ----------------
// Round-17 A/B: + T5 s_setprio around the MFMA cluster (PRIO template arg).
// 3 independently-phased blocks/CU (occ 36%) = the role-diversity regime where
// GEMM2 gained ~5us (r10->r11). Everything else byte-identical to r13.
// Swizzle (rounds 5/6/12/13 verified, 0 conflicts): chunk = 16 rows x 32 elems;
// global source slot (lane&3)^((lane>>3)&3); ds_read slot fs^((row>>1)&3).
template<bool PRIO, bool RELU, bool BF16_OUT>
__global__ __launch_bounds__(256, 4)
void gemm_bt32(const unsigned short* __restrict__ A,  // [M,K] bf16 bits
               const unsigned short* __restrict__ B,  // [N,K] bf16 bits
               const float* __restrict__ bias,        // [N]
               void* __restrict__ Cout,               // [M,N] bf16 or f32
               int M, int N, int K, int gx) {
  constexpr int BK = 32, MF = 4;
  __shared__ __attribute__((aligned(16))) unsigned short As[2][128 * BK];
  __shared__ __attribute__((aligned(16))) unsigned short Bs[2][128 * BK];

  // bijective XCD swizzle (T1/m204)
  const int nwg = gridDim.x;
  const int orig = blockIdx.x;
  const int q = nwg >> 3, r = nwg & 7;
  const int xcd = orig & 7, cidx = orig >> 3;
  const int wgid = (xcd < r ? xcd * (q + 1) : r * (q + 1) + (xcd - r) * q) + cidx;
  const int bx = wgid % gx;
  const int by = wgid / gx;

  const int tid = threadIdx.x;
  const int lane = tid & 63;
  const int wave = tid >> 6;
  const int wr = wave >> 1;
  const int wc = wave & 1;
  const long brow = (long)by * 128;
  const long bcol = (long)bx * 128;

  f32x4 acc[MF][4] = {};

  // staging: chunk = 16 rows x 32 elems (1KB)
  const int srow = lane >> 2;
  const int gslot = ((lane & 3) ^ ((lane >> 3) & 3)) * 8;
  const int fr = lane & 15;
  const int fs = lane >> 4;   // logical 16B k-slot (0..3)

  auto stage = [&](int k0, int b) {
#pragma unroll
    for (int it = 0; it < 2; ++it) {          // A: 8 chunks of 16 rows
      const int c = it * 4 + wave;
      const unsigned short* ga = A + (brow + c * 16 + srow) * (long)K + k0 + gslot;
      __builtin_amdgcn_global_load_lds(
          (const __attribute__((address_space(1))) void*)ga,
          (__attribute__((address_space(3))) void*)(&As[b][c * 512]), 16, 0, 0);
    }
#pragma unroll
    for (int it = 0; it < 2; ++it) {          // B: 8 chunks
      const int c = it * 4 + wave;
      const unsigned short* gb = B + (bcol + c * 16 + srow) * (long)K + k0 + gslot;
      __builtin_amdgcn_global_load_lds(
          (const __attribute__((address_space(1))) void*)gb,
          (__attribute__((address_space(3))) void*)(&Bs[b][c * 512]), 16, 0, 0);
    }
  };

  const int nt = K / BK;
  stage(0, 0);
  stage(BK, 1);

  for (int t = 0; t < nt; ++t) {
    const int b = t & 1;
    if (t < nt - 1) asm volatile("s_waitcnt vmcnt(4)" ::: "memory");
    else            asm volatile("s_waitcnt vmcnt(0)" ::: "memory");
    __builtin_amdgcn_s_barrier();

    const unsigned short* as = &As[b][0];
    const unsigned short* bs = &Bs[b][0];
    bf16x8 a[MF], bb[4];
#pragma unroll
    for (int m = 0; m < MF; ++m) {
      const int row = wr * 64 + m * 16 + fr;
      a[m] = *reinterpret_cast<const bf16x8*>(as + row * BK + ((fs ^ ((row >> 1) & 3)) * 8));
    }
#pragma unroll
    for (int n = 0; n < 4; ++n) {
      const int row = wc * 64 + n * 16 + fr;
      bb[n] = *reinterpret_cast<const bf16x8*>(bs + row * BK + ((fs ^ ((row >> 1) & 3)) * 8));
    }
    if (PRIO) __builtin_amdgcn_s_setprio(1);
#pragma unroll
    for (int m = 0; m < MF; ++m)
#pragma unroll
      for (int n = 0; n < 4; ++n)
        acc[m][n] = __builtin_amdgcn_mfma_f32_16x16x32_bf16(a[m], bb[n], acc[m][n], 0, 0, 0);
    if (PRIO) __builtin_amdgcn_s_setprio(0);

    asm volatile("s_waitcnt lgkmcnt(0)" ::: "memory");
    __builtin_amdgcn_sched_barrier(0);
    __builtin_amdgcn_s_barrier();
    if (t + 2 < nt) stage((t + 2) * BK, b);
  }

  // epilogue: C/D layout col=lane&15, row=(lane>>4)*4+rr  [m89/m91 verified]
  const int fq = lane >> 4;
#pragma unroll
  for (int n = 0; n < 4; ++n) {
    const long col = bcol + wc * 64 + n * 16 + fr;
    const float bv = bias[col];
#pragma unroll
    for (int m = 0; m < MF; ++m) {
#pragma unroll
      for (int rr = 0; rr < 4; ++rr) {
        const long row = brow + wr * 64 + m * 16 + fq * 4 + rr;
        float v = acc[m][n][rr] + bv;
        if (RELU) v = fmaxf(v, 0.0f);
        if (BF16_OUT)
          ((unsigned short*)Cout)[row * N + col] = f2bf(v);
        else
          ((float*)Cout)[row * N + col] = v;
      }
    }
  }
}

// ---------------- GEMM2: round-11/13 kernel frozen (BM=64, BK=64, 3 blk/CU, setprio) ----------------
template<int BM, bool PRIO, bool RELU, bool BF16_OUT>
__global__ __launch_bounds__(256)
void gemm_bt(const unsigned short* __restrict__ A, const unsigned short* __restrict__ B,
             const float* __restrict__ bias, void* __restrict__ Cout,
             int M, int N, int K, int gx) {
  constexpr int BK = 64;
  constexpr int MF = BM / 32;
  __shared__ __attribute__((aligned(16))) unsigned short As[2][BM * BK];
  __shared__ __attribute__((aligned(16))) unsigned short Bs[2][128 * BK];

  const int nwg = gridDim.x;
  const int orig = blockIdx.x;
  const int q = nwg >> 3, r = nwg & 7;
  const int xcd = orig & 7, cidx = orig >> 3;
  const int wgid = (xcd < r ? xcd * (q + 1) : r * (q + 1) + (xcd - r) * q) + cidx;
  const int bx = wgid % gx;
  const int by = wgid / gx;

  const int tid = threadIdx.x;
  const int lane = tid & 63;
  const int wave = tid >> 6;
  const int wr = wave >> 1;
  const int wc = wave & 1;
  const long brow = (long)by * BM;
  const long bcol = (long)bx * 128;

  f32x4 acc[MF][4] = {};

  const int srow = lane >> 3;
  const int gslot = ((lane & 7) ^ (lane >> 3)) * 8;
  const int fr = lane & 15;
  const int fs = lane >> 4;

  auto stage = [&](int k0, int b) {
#pragma unroll
    for (int it = 0; it < BM / 32; ++it) {
      const int c = it * 4 + wave;
      const unsigned short* ga = A + (brow + c * 8 + srow) * (long)K + k0 + gslot;
      __builtin_amdgcn_global_load_lds(
          (const __attribute__((address_space(1))) void*)ga,
          (__attribute__((address_space(3))) void*)(&As[b][c * 512]), 16, 0, 0);
    }
#pragma unroll
    for (int it = 0; it < 4; ++it) {
      const int c = it * 4 + wave;
      const unsigned short* gb = B + (bcol + c * 8 + srow) * (long)K + k0 + gslot;
      __builtin_amdgcn_global_load_lds(
          (const __attribute__((address_space(1))) void*)gb,
          (__attribute__((address_space(3))) void*)(&Bs[b][c * 512]), 16, 0, 0);
    }
  };

  const int nt = K / BK;
  stage(0, 0);
  stage(BK, 1);

  for (int t = 0; t < nt; ++t) {
    const int b = t & 1;
    if (t < nt - 1) {
      if constexpr (BM == 128) asm volatile("s_waitcnt vmcnt(8)" ::: "memory");
      else                     asm volatile("s_waitcnt vmcnt(6)" ::: "memory");
    } else {
      asm volatile("s_waitcnt vmcnt(0)" ::: "memory");
    }
    __builtin_amdgcn_s_barrier();

    const unsigned short* as = &As[b][0];
    const unsigned short* bs = &Bs[b][0];
#pragma unroll
    for (int kk = 0; kk < 2; ++kk) {
      const int s = kk * 4 + fs;
      bf16x8 a[MF], bb[4];
#pragma unroll
      for (int m = 0; m < MF; ++m) {
        const int row = wr * (MF * 16) + m * 16 + fr;
        a[m] = *reinterpret_cast<const bf16x8*>(as + row * BK + ((s ^ (row & 7)) * 8));
      }
#pragma unroll
      for (int n = 0; n < 4; ++n) {
        const int row = wc * 64 + n * 16 + fr;
        bb[n] = *reinterpret_cast<const bf16x8*>(bs + row * BK + ((s ^ (row & 7)) * 8));
      }
      if (PRIO) __builtin_amdgcn_s_setprio(1);
#pragma unroll
      for (int m = 0; m < MF; ++m)
#pragma unroll
        for (int n = 0; n < 4; ++n)
          acc[m][n] = __builtin_amdgcn_mfma_f32_16x16x32_bf16(a[m], bb[n], acc[m][n], 0, 0, 0);
      if (PRIO) __builtin_amdgcn_s_setprio(0);
    }

    asm volatile("s_waitcnt lgkmcnt(0)" ::: "memory");
    __builtin_amdgcn_sched_barrier(0);
    __builtin_amdgcn_s_barrier();
    if (t + 2 < nt) stage((t + 2) * BK, b);
  }

  const int fq = lane >> 4;
#pragma unroll
  for (int n = 0; n < 4; ++n) {
    const long col = bcol + wc * 64 + n * 16 + fr;
    const float bv = bias[col];
#pragma unroll
    for (int m = 0; m < MF; ++m) {
#pragma unroll
      for (int rr = 0; rr < 4; ++rr) {
        const long row = brow + wr * (MF * 16) + m * 16 + fq * 4 + rr;
        float v = acc[m][n][rr] + bv;
        if (RELU) v = fmaxf(v, 0.0f);
        if (BF16_OUT)
          ((unsigned short*)Cout)[row * N + col] = f2bf(v);
        else
          ((float*)Cout)[row * N + col] = v;
      }
    }
  }
}

extern "C" void kernel_launch(void* const* d_in, const int* in_sizes, int n_in,
                              void* d_out, int out_size, void* d_ws, size_t ws_size,
                              hipStream_t stream) {
  const float* x  = (const float*)d_in[0];
  const float* w1 = (const float*)d_in[1];
  const float* b1 = (const float*)d_in[2];
  const float* w2 = (const float*)d_in[3];
  const float* b2 = (const float*)d_in[4];
  const int* bits = (const int*)d_in[5];

  const int M = 64 * 196;  // 12544 tokens
  const int D = 768, H = 3072;
  const int nx = M * D;
  const int nw1 = H * D;

  char* ws = (char*)d_ws;
  unsigned short* xb  = (unsigned short*)(ws + 256);
  unsigned short* w1q = (unsigned short*)(ws + 256 + (size_t)nx * 2);
  unsigned short* w2q = (unsigned short*)(ws + 256 + (size_t)nx * 2 + (size_t)nw1 * 2);
  unsigned short* hb  = (unsigned short*)(ws + 256 + (size_t)nx * 2 + (size_t)nw1 * 4);
  // pmax[2][512] aliased over hb's head: dead by the time GEMM1 writes hb
  // (prep -> quant2 -> GEMM1 are stream-serial; rewritten every call).
  unsigned int* pmax = (unsigned int*)hb;

  prep_kernel<<<dim3(512, 3), 256, 0, stream>>>(w1, w2, x, nw1 / 4, nx / 4, pmax, xb);
  quant2_kernel<<<dim3(512, 2), 256, 0, stream>>>(w1, w2, nw1 / 4, pmax, bits, w1q, w2q);

  // GEMM1: h = relu(x @ w1^T + b1), [12544,3072] bf16 ; 24x98 = 2352 blocks,
  // nt=24, 32KB LDS (r13 config) + T5 setprio A/B
  gemm_bt32<true, true, true><<<(H / 128) * (M / 128), 256, 0, stream>>>(
      xb, w1q, b1, hb, M, H, D, H / 128);
  // GEMM2: out = h @ w2^T + b2, [12544,768] f32 ; 6x196 = 1176 blocks, nt=48,
  // 48KB LDS -> 3 blk/CU (round-11/13 frozen)
  gemm_bt<64, true, false, false><<<(D / 128) * (M / 64), 256, 0, stream>>>(
      hb, w2q, b2, d_out, M, D, H, D / 128);
}